// Round 19
// baseline (83.555 us; speedup 1.0000x reference)
//
#include <hip/hip_runtime.h>
#include <hip/hip_bf16.h>
#include <math.h>

#define TT 128
#define IN_CH 32
#define NPATH 256
#define SIGCH 7380
#define SIGP 7392
#define K1 29520
#define N1 512
#define N2 256

typedef __attribute__((ext_vector_type(8))) short bf16x8;
typedef __attribute__((ext_vector_type(4))) float f32x4;

static __device__ __forceinline__ unsigned pack2bf(float a, float b) {
    union { __hip_bfloat162 h2; unsigned u; } cv;
    cv.h2.x = __float2bfloat16(a);
    cv.h2.y = __float2bfloat16(b);
    return cv.u;
}

// ---------------- Kernel 1a: conv + quarter-scan (4-way Chen block split) ----------------
// Grid = (NPATH, 4): block (p,q) scans steps [32q, 32q+32) of path p with 243
// active threads (same STEP4 inner loop as r16) and writes its partial sig
// (levels 1-4) to psig[p*4+q][7392]. 1024 blocks -> 4 blocks/CU, 16 waves/CU
// (vs 1 block/CU before): 4x parallelism, 1/4 the serial chain.
__global__ __launch_bounds__(256) void sigscan_kernel(const float* __restrict__ x,
        const float* __restrict__ cw, const float* __restrict__ cb,
        float* __restrict__ psig /*[1024][7392]*/) {
    __shared__ float incT[9][36];
    const int p = blockIdx.x;
    const int q4 = blockIdx.y;           // quarter 0..3
    const int b = p >> 2, oc = p & 3;
    const int tid = threadIdx.x;

    const float4 wv = *(const float4*)(cw + oc * 4);
    const float bias = cb[oc];
    const float* xb = x + (long)b * TT * IN_CH;
    const int t0 = q4 * 32;

    {   // staging: one (t_local, ch) per thread
        const int tl = tid >> 3, ch = tid & 7;
        const int t = t0 + tl;
        const float4 xa = *(const float4*)(xb + t * IN_CH + ch * 4);
        float v = xa.x * wv.x + xa.y * wv.y + xa.z * wv.z + xa.w * wv.w + bias;
        if (t > 0) {
            const float4 xm = *(const float4*)(xb + (t - 1) * IN_CH + ch * 4);
            v -= xm.x * wv.x + xm.y * wv.y + xm.z * wv.z + xm.w * wv.w + bias;
        }
        incT[1 + ch][tl] = v;
        if (tid < 32) incT[0][tid] = (t0 + tid) ? (1.f / 127.f) : 0.f;
    }
    __syncthreads();

    const int gtid = tid;
    const bool act = gtid < 243;
    const int base3 = 3 * gtid;
    const int i1 = base3 / 81;
    const int i2 = (base3 / 9) % 9;
    const int i30 = base3 % 9;

    float S4[3][9] = {};
    float s3[3] = {0.f, 0.f, 0.f};
    float s2 = 0.f, s1 = 0.f;

#define LD(R, T4) (*(const float4*)&incT[(R)][(T4)])
#define STEP4(CMP) do { \
    const float E1 = e1v.CMP, E2 = e2v.CMP; \
    const float F0 = f0v.CMP, F1 = f1v.CMP, F2 = f2v.CMP; \
    const float t12 = E1 * E2; \
    const float s1d2 = s1 * E2; \
    const float Ak = t12 * (1.f / 24.f) + s1d2 * (1.f / 6.f) + s2 * 0.5f; \
    const float Bk = t12 * (1.f / 6.f) + s1d2 * 0.5f + s2; \
    const float K0 = F0 * Ak + s3[0]; \
    const float K1v = F1 * Ak + s3[1]; \
    const float K2v = F2 * Ak + s3[2]; \
    _Pragma("unroll") \
    for (int c = 0; c < 9; ++c) { \
        const float Ac = A4[c].CMP; \
        S4[0][c] += K0 * Ac; S4[1][c] += K1v * Ac; S4[2][c] += K2v * Ac; \
    } \
    s3[0] += Bk * F0; s3[1] += Bk * F1; s3[2] += Bk * F2; \
    s2 += E2 * (0.5f * E1 + s1); \
    s1 += E1; \
} while (0)

    if (act) {
        for (int gg = 0; gg < 8; ++gg) {
            const int t4 = gg * 4;
            float4 A4[9];
#pragma unroll
            for (int c = 0; c < 9; ++c) A4[c] = LD(c, t4);
            const float4 e1v = LD(i1, t4), e2v = LD(i2, t4);
            const float4 f0v = LD(i30, t4), f1v = LD(i30 + 1, t4), f2v = LD(i30 + 2, t4);
            STEP4(x); STEP4(y); STEP4(z); STEP4(w);
        }
        // write partial sig (coalesced-ish: 27 consecutive floats per thread)
        float* d = psig + (long)(p * 4 + q4) * SIGP;
        if (i2 == 0 && i30 == 0) d[i1] = s1;
        if (i30 == 0) d[9 + i1 * 9 + i2] = s2;
        d[90 + base3 + 0] = s3[0];
        d[90 + base3 + 1] = s3[1];
        d[90 + base3 + 2] = s3[2];
#pragma unroll
        for (int qq = 0; qq < 3; ++qq)
#pragma unroll
            for (int c = 0; c < 9; ++c)
                d[819 + (base3 + qq) * 9 + c] = S4[qq][c];
    }
#undef STEP4
#undef LD
}

// ---------------- Kernel 1b: Chen merge of 4 quarters ----------------
// 256 blocks x 256 thr: block p computes ((S0 (x) S1) (x) S2) (x) S3.
// A-side lives in regs (thread's own triple slices); each round stages the
// B-side row into LDS (coalesced) and merges. Final write row-major.
__global__ __launch_bounds__(256) void sigmerge_kernel(const float* __restrict__ psig,
        float* __restrict__ sig /*[256][7380]*/) {
    __shared__ float sbuf[SIGP];
    const int p = blockIdx.x;
    const int tid = threadIdx.x;
    const bool act = tid < 243;
    const int base3 = 3 * tid;
    const int i1 = base3 / 81;
    const int i2 = (base3 / 9) % 9;
    const int i30 = base3 % 9;

    float S4[3][9];
    float s3[3], s2 = 0.f, s1 = 0.f;

    // load A-state = quarter 0
    const float* pA = psig + (long)(p * 4) * SIGP;
    if (act) {
        s1 = pA[i1];
        s2 = pA[9 + i1 * 9 + i2];
#pragma unroll
        for (int qq = 0; qq < 3; ++qq) s3[qq] = pA[90 + base3 + qq];
#pragma unroll
        for (int qq = 0; qq < 3; ++qq)
#pragma unroll
            for (int c = 0; c < 9; ++c)
                S4[qq][c] = pA[819 + (base3 + qq) * 9 + c];
    }

    for (int r = 1; r < 4; ++r) {
        __syncthreads();
        const float* pB = psig + (long)(p * 4 + r) * SIGP;
        for (int i = tid; i < SIGP / 4; i += 256)
            *(float4*)&sbuf[i * 4] = *(const float4*)(pB + i * 4);
        __syncthreads();
        if (act) {
            float S1B[9];
#pragma unroll
            for (int c = 0; c < 9; ++c) S1B[c] = sbuf[c];
#pragma unroll
            for (int qq = 0; qq < 3; ++qq) {
                const float* r2 = &sbuf[9 + (i30 + qq) * 9];
                const float* r3 = &sbuf[90 + (i2 * 9 + i30 + qq) * 9];
                const float* r4 = &sbuf[819 + (base3 + qq) * 9];
#pragma unroll
                for (int c = 0; c < 9; ++c)
                    S4[qq][c] += s3[qq] * S1B[c] + s2 * r2[c] + s1 * r3[c] + r4[c];
            }
#pragma unroll
            for (int qq = 0; qq < 3; ++qq)
                s3[qq] += s2 * S1B[i30 + qq] + s1 * sbuf[9 + i2 * 9 + i30 + qq]
                        + sbuf[90 + (i1 * 9 + i2) * 9 + i30 + qq];
            s2 += s1 * S1B[i2] + sbuf[9 + i1 * 9 + i2];
            s1 += S1B[i1];
        }
    }

    if (act) {
        float* sp = sig + (long)p * SIGCH;
        if (i2 == 0 && i30 == 0) sp[i1] = s1;
        if (i30 == 0) sp[9 + base3 / 9] = s2;
        sp[90 + base3 + 0] = s3[0];
        sp[90 + base3 + 1] = s3[1];
        sp[90 + base3 + 2] = s3[2];
#pragma unroll
        for (int qq = 0; qq < 3; qq++)
#pragma unroll
            for (int l = 0; l < 9; l++)
                sp[819 + (base3 + qq) * 9 + l] = S4[qq][l];
    }
}

// ---------------- Kernel 2: GEMM1 partials via bf16 MFMA (unchanged r18) ----------------
__global__ __launch_bounds__(256) void gemm1_kernel(const float* __restrict__ zsig,
        const float* __restrict__ w0, float* __restrict__ part, int nsub) {
    __shared__ unsigned short za[64][136];
    __shared__ unsigned short wb[64][136];
    const int nq = blockIdx.x;            // 0..7
    const int n0 = nq * 64;
    const int tid = threadIdx.x;
    const int lane = tid & 63;
    const int wvid = __builtin_amdgcn_readfirstlane(tid >> 6);  // 0..3
    const int r0 = wvid * 16;
    const int rA = lane & 15, gr = lane >> 4;

    {
        const int row = tid >> 2, off = 120 + 2 * (tid & 3);
        *(unsigned*)&za[row][off] = 0u;
        *(unsigned*)&wb[row][off] = 0u;
    }

    f32x4 acc[4];
#pragma unroll
    for (int t = 0; t < 4; ++t) acc[t] = (f32x4){0.f, 0.f, 0.f, 0.f};

    for (int s = 0; s < nsub; ++s) {
        const int kb = (blockIdx.y * nsub + s) * 120;
        if (s) __syncthreads();
#pragma unroll
        for (int j = 0; j < 16; ++j) {
            const int i = tid + j * 256;
            const int row = i >> 6, kp = i & 63;
            if (kp < 60) {
                const float2 v = *(const float2*)(zsig + (long)row * K1 + kb + 2 * kp);
                *(unsigned*)&za[row][2 * kp] = pack2bf(v.x, v.y);
            }
        }
#pragma unroll
        for (int j = 0; j < 16; ++j) {
            const int i = tid + j * 256;
            const int c = i & 63, kq = i >> 6;
            if (kq < 60) {
                const float a = w0[(long)(kb + 2 * kq) * N1 + n0 + c];
                const float bvl = w0[(long)(kb + 2 * kq + 1) * N1 + n0 + c];
                *(unsigned*)&wb[c][2 * kq] = pack2bf(a, bvl);
            }
        }
        __syncthreads();
#pragma unroll
        for (int ks = 0; ks < 4; ++ks) {
            const bf16x8 af = *(const bf16x8*)&za[r0 + rA][ks * 32 + gr * 8];
#pragma unroll
            for (int t = 0; t < 4; ++t) {
                const bf16x8 bf = *(const bf16x8*)&wb[16 * t + rA][ks * 32 + gr * 8];
                acc[t] = __builtin_amdgcn_mfma_f32_16x16x32_bf16(af, bf, acc[t], 0, 0, 0);
            }
        }
    }

    float* pp = part + ((long)blockIdx.y * 64 + r0 + 4 * gr) * N1 + n0 + rA;
#pragma unroll
    for (int t = 0; t < 4; ++t)
#pragma unroll
        for (int j = 0; j < 4; ++j)
            pp[(long)j * N1 + 16 * t] = acc[t][j];
}

// ---------------- Kernel 3: reduce partials + bias + sigmoid ----------------
__global__ __launch_bounds__(256) void red1_kernel(const float* __restrict__ part,
        const float* __restrict__ b0v, float* __restrict__ z1, int ksplit) {
    __shared__ float4 red[256];
    const int tid = threadIdx.x;
    const int cellL = tid & 15, slice = tid >> 4;
    const int cell = blockIdx.x * 16 + cellL;
    const int per = (ksplit + 15) >> 4;
    const int ks = slice * per, ke = min(ksplit, ks + per);
    float4 a = make_float4(0.f, 0.f, 0.f, 0.f);
    for (int kc = ks; kc < ke; kc++) {
        const float4 pv = *(const float4*)(part + ((long)kc * 8192 + cell) * 4);
        a.x += pv.x; a.y += pv.y; a.z += pv.z; a.w += pv.w;
    }
    red[tid] = a;
    __syncthreads();
    if (tid < 128) { float4 o = red[tid + 128]; red[tid].x += o.x; red[tid].y += o.y; red[tid].z += o.z; red[tid].w += o.w; }
    __syncthreads();
    if (tid < 64) { float4 o = red[tid + 64]; red[tid].x += o.x; red[tid].y += o.y; red[tid].z += o.z; red[tid].w += o.w; }
    __syncthreads();
    if (tid < 32) { float4 o = red[tid + 32]; red[tid].x += o.x; red[tid].y += o.y; red[tid].z += o.z; red[tid].w += o.w; }
    __syncthreads();
    if (tid < 16) {
        float4 sum = red[tid];
        float4 o = red[tid + 16];
        sum.x += o.x; sum.y += o.y; sum.z += o.z; sum.w += o.w;
        const float4 bv = *(const float4*)(b0v + (cell & 127) * 4);
        float4 r;
        r.x = 1.f / (1.f + expf(-(sum.x + bv.x)));
        r.y = 1.f / (1.f + expf(-(sum.y + bv.y)));
        r.z = 1.f / (1.f + expf(-(sum.z + bv.z)));
        r.w = 1.f / (1.f + expf(-(sum.w + bv.w)));
        *(float4*)(z1 + cell * 4) = r;
    }
}

// ---------------- Kernel 4: GEMM2 + bias + sigmoid ----------------
__global__ __launch_bounds__(256) void gemm2_kernel(const float* __restrict__ z1,
        const float* __restrict__ w1, const float* __restrict__ b1v,
        float* __restrict__ z2) {
    __shared__ float red[256];
    const int m = blockIdx.x >> 2, nq = blockIdx.x & 3;
    const int tid = threadIdx.x;
    const int c = tid & 63, s = tid >> 6;
    const int n = nq * 64 + c;
    const float* zr = z1 + m * N1 + s * 128;
    const float* wr = w1 + (long)(s * 128) * N2 + n;
    float acc = 0.f;
#pragma unroll 16
    for (int k = 0; k < 128; k++) acc += zr[k] * wr[(long)k * N2];
    red[tid] = acc;
    __syncthreads();
    if (tid < 128) red[tid] += red[tid + 128];
    __syncthreads();
    if (tid < 64) {
        float sum = red[tid] + red[tid + 64] + b1v[n];
        z2[m * N2 + n] = 1.f / (1.f + expf(-sum));
    }
}

// ---------------- Kernel 5: GEMM3 + log_softmax ----------------
__global__ __launch_bounds__(64) void head_kernel(const float* __restrict__ z2,
        const float* __restrict__ w2, const float* __restrict__ b2v,
        float* __restrict__ out) {
    const int m = blockIdx.x;
    const int tid = threadIdx.x;
    __shared__ float logits[10];
    if (tid < 10) {
        float s = b2v[tid];
        const float* zr = z2 + m * N2;
#pragma unroll 8
        for (int k = 0; k < N2; k++) s += zr[k] * w2[k * 10 + tid];
        logits[tid] = s;
    }
    __syncthreads();
    if (tid == 0) {
        float mx = logits[0];
        for (int j = 1; j < 10; j++) mx = fmaxf(mx, logits[j]);
        float sum = 0.f;
        for (int j = 0; j < 10; j++) sum += expf(logits[j] - mx);
        const float lse = mx + logf(sum);
        for (int j = 0; j < 10; j++) out[m * 10 + j] = logits[j] - lse;
    }
}

extern "C" void kernel_launch(void* const* d_in, const int* in_sizes, int n_in,
                              void* d_out, int out_size, void* d_ws, size_t ws_size,
                              hipStream_t stream) {
    const float* x  = (const float*)d_in[0];
    const float* cw = (const float*)d_in[1];
    const float* cb = (const float*)d_in[2];
    const float* w0 = (const float*)d_in[3];
    const float* b0 = (const float*)d_in[4];
    const float* w1 = (const float*)d_in[5];
    const float* b1 = (const float*)d_in[6];
    const float* w2 = (const float*)d_in[7];
    const float* b2 = (const float*)d_in[8];

    // tiered K-split: ksplit * nsub * 120 = 29520
    const size_t fixed = (size_t)NPATH * SIGCH + (size_t)NPATH * 4 * SIGP
                       + 64 * N1 + 64 * N2;
    int ksplit = 41, nsub = 6;
    if (ws_size >= (fixed + (size_t)123 * 64 * N1) * 4)      { ksplit = 123; nsub = 2; }
    else if (ws_size >= (fixed + (size_t)82 * 64 * N1) * 4)  { ksplit = 82;  nsub = 3; }

    float* ws   = (float*)d_ws;
    float* sigb = ws;                                // 256 x 7380 row-major
    float* psig = sigb + (long)NPATH * SIGCH;        // 1024 x 7392 partials
    float* part = psig + (long)NPATH * 4 * SIGP;     // ksplit*64*512
    float* z1   = part + (long)ksplit * 64 * N1;     // 64*512
    float* z2   = z1 + 64 * N1;                      // 64*256
    float* out  = (float*)d_out;

    sigscan_kernel<<<dim3(NPATH, 4), 256, 0, stream>>>(x, cw, cb, psig);
    sigmerge_kernel<<<NPATH, 256, 0, stream>>>(psig, sigb);
    gemm1_kernel<<<dim3(8, ksplit), 256, 0, stream>>>(sigb, w0, part, nsub);
    red1_kernel<<<512, 256, 0, stream>>>(part, b0, z1, ksplit);
    gemm2_kernel<<<256, 256, 0, stream>>>(z1, w1, b1, z2);
    head_kernel<<<64, 64, 0, stream>>>(z2, w2, b2, out);
}

// Round 20
// 72.366 us; speedup vs baseline: 1.1546x; 1.1546x over previous
//
#include <hip/hip_runtime.h>
#include <hip/hip_bf16.h>
#include <math.h>

#define TT 128
#define IN_CH 32
#define NPATH 256
#define SIGCH 7380
#define K1 29520
#define N1 512
#define N2 256

typedef __attribute__((ext_vector_type(8))) short bf16x8;
typedef __attribute__((ext_vector_type(8))) unsigned short u16x8;
typedef __attribute__((ext_vector_type(4))) float f32x4;

static __device__ __forceinline__ unsigned pack2bf(float a, float b) {
    union { __hip_bfloat162 h2; unsigned u; } cv;
    cv.h2.x = __float2bfloat16(a);
    cv.h2.y = __float2bfloat16(b);
    return cv.u;
}

// ---------------- Kernel 1: conv + time-augment + depth-4 signature ----------------
// r16 monolithic structure (512 thr, 2-way Chen split; sig measured ~3-5us).
// Emits bf16 directly: gemm1 is the only consumer and would convert anyway.
__global__ __launch_bounds__(512, 1) void sig_kernel(const float* __restrict__ x,
        const float* __restrict__ cw, const float* __restrict__ cb,
        __hip_bfloat16* __restrict__ sigbf /*[256][7380] bf16*/) {
    __shared__ float incT[9][132];
    __shared__ __align__(16) float sb1[12];
    __shared__ __align__(16) float sb2[9][12];
    __shared__ __align__(16) float sb3[81][12];
    __shared__ __align__(16) float sb4[729][12];
    const int p = blockIdx.x;
    const int b = p >> 2, oc = p & 3;
    const int tid = threadIdx.x;

    const float4 wv = *(const float4*)(cw + oc * 4);
    const float bias = cb[oc];
    const float* xb = x + (long)b * TT * IN_CH;

    for (int it = tid; it < TT * 8; it += 512) {
        const int t = it >> 3, ch = it & 7;
        const float4 xa = *(const float4*)(xb + t * IN_CH + ch * 4);
        float v = xa.x * wv.x + xa.y * wv.y + xa.z * wv.z + xa.w * wv.w + bias;
        if (t > 0) {
            const float4 xm = *(const float4*)(xb + (t - 1) * IN_CH + ch * 4);
            v -= xm.x * wv.x + xm.y * wv.y + xm.z * wv.z + xm.w * wv.w + bias;
        }
        incT[1 + ch][t] = v;
    }
    if (tid < TT) incT[0][tid] = tid ? (1.f / 127.f) : 0.f;
    __syncthreads();

    const int g = tid >> 8;
    const int gtid = tid & 255;
    const bool act = gtid < 243;
    const int base3 = 3 * gtid;
    const int i1 = base3 / 81;
    const int i2 = (base3 / 9) % 9;
    const int i30 = base3 % 9;

    float S4[3][9] = {};
    float s3[3] = {0.f, 0.f, 0.f};
    float s2 = 0.f, s1 = 0.f;

#define LD(R, T4) (*(const float4*)&incT[(R)][(T4)])
#define STEP4(CMP) do { \
    const float E1 = e1v.CMP, E2 = e2v.CMP; \
    const float F0 = f0v.CMP, F1 = f1v.CMP, F2 = f2v.CMP; \
    const float t12 = E1 * E2; \
    const float s1d2 = s1 * E2; \
    const float Ak = t12 * (1.f / 24.f) + s1d2 * (1.f / 6.f) + s2 * 0.5f; \
    const float Bk = t12 * (1.f / 6.f) + s1d2 * 0.5f + s2; \
    const float K0 = F0 * Ak + s3[0]; \
    const float K1v = F1 * Ak + s3[1]; \
    const float K2v = F2 * Ak + s3[2]; \
    _Pragma("unroll") \
    for (int c = 0; c < 9; ++c) { \
        const float Ac = A4[c].CMP; \
        S4[0][c] += K0 * Ac; S4[1][c] += K1v * Ac; S4[2][c] += K2v * Ac; \
    } \
    s3[0] += Bk * F0; s3[1] += Bk * F1; s3[2] += Bk * F2; \
    s2 += E2 * (0.5f * E1 + s1); \
    s1 += E1; \
} while (0)

    if (act) {
        const int t0g = g * 64;
        for (int gg = 0; gg < 16; ++gg) {
            const int t4 = t0g + gg * 4;
            float4 A4[9];
#pragma unroll
            for (int c = 0; c < 9; ++c) A4[c] = LD(c, t4);
            const float4 e1v = LD(i1, t4), e2v = LD(i2, t4);
            const float4 f0v = LD(i30, t4), f1v = LD(i30 + 1, t4), f2v = LD(i30 + 2, t4);
            STEP4(x); STEP4(y); STEP4(z); STEP4(w);
        }
    }
#undef STEP4
#undef LD

    if (act && g == 1) {
        if (i2 == 0 && i30 == 0) sb1[i1] = s1;
        if (i30 == 0) sb2[i1][i2] = s2;
#pragma unroll
        for (int q = 0; q < 3; ++q) sb3[i1 * 9 + i2][i30 + q] = s3[q];
#pragma unroll
        for (int q = 0; q < 3; ++q)
#pragma unroll
            for (int c = 0; c < 9; ++c) sb4[base3 + q][c] = S4[q][c];
    }
    __syncthreads();

    if (act && g == 0) {
        float S1B[9];
#pragma unroll
        for (int c = 0; c < 9; ++c) S1B[c] = sb1[c];
#pragma unroll
        for (int q = 0; q < 3; ++q) {
            const float* r2 = sb2[i30 + q];
            const float* r3 = sb3[i2 * 9 + i30 + q];
            const float* r4 = sb4[base3 + q];
#pragma unroll
            for (int c = 0; c < 9; ++c)
                S4[q][c] += s3[q] * S1B[c] + s2 * r2[c] + s1 * r3[c] + r4[c];
        }
#pragma unroll
        for (int q = 0; q < 3; ++q)
            s3[q] += s2 * S1B[i30 + q] + s1 * sb2[i2][i30 + q] + sb3[i1 * 9 + i2][i30 + q];
        s2 += s1 * S1B[i2] + sb2[i1][i2];
        s1 += S1B[i1];

        __hip_bfloat16* sp = sigbf + (long)p * SIGCH;
        if (i2 == 0 && i30 == 0) sp[i1] = __float2bfloat16(s1);
        if (i30 == 0) sp[9 + base3 / 9] = __float2bfloat16(s2);
        sp[90 + base3 + 0] = __float2bfloat16(s3[0]);
        sp[90 + base3 + 1] = __float2bfloat16(s3[1]);
        sp[90 + base3 + 2] = __float2bfloat16(s3[2]);
#pragma unroll
        for (int q = 0; q < 3; q++)
#pragma unroll
            for (int l = 0; l < 9; l++)
                sp[819 + (base3 + q) * 9 + l] = __float2bfloat16(S4[q][l]);
    }
}

// ---------------- Kernel 2: GEMM1 partials via bf16 MFMA, vectorized staging ----------------
// 64x64 tile (35KB LDS -> 4 blocks/CU). Grid = 8 col-groups x ksplit.
// z: already bf16 -> pure ushort8 copies (16B/lane, 4 iters exact).
// w: float4-pair loads (16B/lane) + pack to bf16 (4 iters exact).
__global__ __launch_bounds__(256) void gemm1_kernel(const unsigned short* __restrict__ zsig,
        const float* __restrict__ w0, float* __restrict__ part, int nsub) {
    __shared__ unsigned short za[64][136];
    __shared__ unsigned short wb[64][136];
    const int nq = blockIdx.x;            // 0..7
    const int n0 = nq * 64;
    const int tid = threadIdx.x;
    const int lane = tid & 63;
    const int wvid = __builtin_amdgcn_readfirstlane(tid >> 6);  // 0..3
    const int r0 = wvid * 16;
    const int rA = lane & 15, gr = lane >> 4;

    {   // zero k-pad [120,128) once
        const int row = tid >> 2, off = 120 + 2 * (tid & 3);
        *(unsigned*)&za[row][off] = 0u;
        *(unsigned*)&wb[row][off] = 0u;
    }

    f32x4 acc[4];
#pragma unroll
    for (int t = 0; t < 4; ++t) acc[t] = (f32x4){0.f, 0.f, 0.f, 0.f};

    for (int s = 0; s < nsub; ++s) {
        const int kb = (blockIdx.y * nsub + s) * 120;
        if (s) __syncthreads();
        // stage z: 64 rows x 15 ushort8 segments = 960 (16B/lane)
#pragma unroll
        for (int j = 0; j < 4; ++j) {
            const int i = tid + j * 256;
            if (i < 960) {
                const int row = i / 15, seg = i % 15;
                *(u16x8*)&za[row][seg * 8] =
                    *(const u16x8*)(zsig + (long)row * K1 + kb + seg * 8);
            }
        }
        // stage w: 60 kp x 16 col-quads = 960; two float4 rows -> 4 packed dwords
#pragma unroll
        for (int j = 0; j < 4; ++j) {
            const int i = tid + j * 256;
            if (i < 960) {
                const int kp = i >> 4, cq = (i & 15) * 4;
                const float4 ra = *(const float4*)(w0 + (long)(kb + 2 * kp) * N1 + n0 + cq);
                const float4 rb = *(const float4*)(w0 + (long)(kb + 2 * kp + 1) * N1 + n0 + cq);
                *(unsigned*)&wb[cq + 0][2 * kp] = pack2bf(ra.x, rb.x);
                *(unsigned*)&wb[cq + 1][2 * kp] = pack2bf(ra.y, rb.y);
                *(unsigned*)&wb[cq + 2][2 * kp] = pack2bf(ra.z, rb.z);
                *(unsigned*)&wb[cq + 3][2 * kp] = pack2bf(ra.w, rb.w);
            }
        }
        __syncthreads();
#pragma unroll
        for (int ks = 0; ks < 4; ++ks) {
            const bf16x8 af = *(const bf16x8*)&za[r0 + rA][ks * 32 + gr * 8];
#pragma unroll
            for (int t = 0; t < 4; ++t) {
                const bf16x8 bf = *(const bf16x8*)&wb[16 * t + rA][ks * 32 + gr * 8];
                acc[t] = __builtin_amdgcn_mfma_f32_16x16x32_bf16(af, bf, acc[t], 0, 0, 0);
            }
        }
    }

    // D: row = r0 + 4*gr + j, col = n0 + 16*t + rA
    float* pp = part + ((long)blockIdx.y * 64 + r0 + 4 * gr) * N1 + n0 + rA;
#pragma unroll
    for (int t = 0; t < 4; ++t)
#pragma unroll
        for (int j = 0; j < 4; ++j)
            pp[(long)j * N1 + 16 * t] = acc[t][j];
}

// ---------------- Kernel 3: reduce partials + bias + sigmoid ----------------
__global__ __launch_bounds__(256) void red1_kernel(const float* __restrict__ part,
        const float* __restrict__ b0v, float* __restrict__ z1, int ksplit) {
    __shared__ float4 red[256];
    const int tid = threadIdx.x;
    const int cellL = tid & 15, slice = tid >> 4;
    const int cell = blockIdx.x * 16 + cellL;
    const int per = (ksplit + 15) >> 4;
    const int ks = slice * per, ke = min(ksplit, ks + per);
    float4 a = make_float4(0.f, 0.f, 0.f, 0.f);
    for (int kc = ks; kc < ke; kc++) {
        const float4 pv = *(const float4*)(part + ((long)kc * 8192 + cell) * 4);
        a.x += pv.x; a.y += pv.y; a.z += pv.z; a.w += pv.w;
    }
    red[tid] = a;
    __syncthreads();
    if (tid < 128) { float4 o = red[tid + 128]; red[tid].x += o.x; red[tid].y += o.y; red[tid].z += o.z; red[tid].w += o.w; }
    __syncthreads();
    if (tid < 64) { float4 o = red[tid + 64]; red[tid].x += o.x; red[tid].y += o.y; red[tid].z += o.z; red[tid].w += o.w; }
    __syncthreads();
    if (tid < 32) { float4 o = red[tid + 32]; red[tid].x += o.x; red[tid].y += o.y; red[tid].z += o.z; red[tid].w += o.w; }
    __syncthreads();
    if (tid < 16) {
        float4 sum = red[tid];
        float4 o = red[tid + 16];
        sum.x += o.x; sum.y += o.y; sum.z += o.z; sum.w += o.w;
        const float4 bv = *(const float4*)(b0v + (cell & 127) * 4);
        float4 r;
        r.x = 1.f / (1.f + expf(-(sum.x + bv.x)));
        r.y = 1.f / (1.f + expf(-(sum.y + bv.y)));
        r.z = 1.f / (1.f + expf(-(sum.z + bv.z)));
        r.w = 1.f / (1.f + expf(-(sum.w + bv.w)));
        *(float4*)(z1 + cell * 4) = r;
    }
}

// ---------------- Kernel 4: fused GEMM2+sigmoid+GEMM3+log_softmax ----------------
__global__ __launch_bounds__(256) void tail_kernel(const float* __restrict__ z1,
        const float* __restrict__ w1, const float* __restrict__ b1v,
        const float* __restrict__ w2, const float* __restrict__ b2v,
        float* __restrict__ out) {
    __shared__ float z2row[N2];
    __shared__ float red[160];
    __shared__ float logits[10];
    const int m = blockIdx.x;
    const int tid = threadIdx.x;
    const float* zr = z1 + m * N1;
    float acc = b1v[tid];
#pragma unroll 8
    for (int k = 0; k < N1; k++) acc += zr[k] * w1[(long)k * N2 + tid];
    z2row[tid] = 1.f / (1.f + expf(-acc));
    __syncthreads();
    if (tid < 160) {
        const int j = tid >> 4, s = tid & 15;
        float p = 0.f;
#pragma unroll
        for (int kk = 0; kk < 16; kk++) {
            const int k = s * 16 + kk;
            p += z2row[k] * w2[k * 10 + j];
        }
        red[tid] = p;
    }
    __syncthreads();
    if (tid < 10) {
        float lg = b2v[tid];
#pragma unroll
        for (int s = 0; s < 16; s++) lg += red[tid * 16 + s];
        logits[tid] = lg;
    }
    __syncthreads();
    if (tid == 0) {
        float mx = logits[0];
        for (int j = 1; j < 10; j++) mx = fmaxf(mx, logits[j]);
        float sum = 0.f;
        for (int j = 0; j < 10; j++) sum += expf(logits[j] - mx);
        const float lse = mx + logf(sum);
        for (int j = 0; j < 10; j++) out[m * 10 + j] = logits[j] - lse;
    }
}

extern "C" void kernel_launch(void* const* d_in, const int* in_sizes, int n_in,
                              void* d_out, int out_size, void* d_ws, size_t ws_size,
                              hipStream_t stream) {
    const float* x  = (const float*)d_in[0];
    const float* cw = (const float*)d_in[1];
    const float* cb = (const float*)d_in[2];
    const float* w0 = (const float*)d_in[3];
    const float* b0 = (const float*)d_in[4];
    const float* w1 = (const float*)d_in[5];
    const float* b1 = (const float*)d_in[6];
    const float* w2 = (const float*)d_in[7];
    const float* b2 = (const float*)d_in[8];

    // sig stored as bf16 (1,889,280 ushorts = 944,640 floats)
    const size_t sig_floats = (size_t)NPATH * SIGCH / 2;
    const size_t fixed = sig_floats + 64 * N1 + 64 * N2;
    int ksplit = 41, nsub = 6;
    if (ws_size >= (fixed + (size_t)123 * 64 * N1) * 4)      { ksplit = 123; nsub = 2; }
    else if (ws_size >= (fixed + (size_t)82 * 64 * N1) * 4)  { ksplit = 82;  nsub = 3; }

    float* ws   = (float*)d_ws;
    unsigned short* sigbf = (unsigned short*)ws;      // 256 x 7380 bf16
    float* part = ws + sig_floats;                    // ksplit*64*512
    float* z1   = part + (long)ksplit * 64 * N1;      // 64*512
    float* out  = (float*)d_out;

    sig_kernel<<<NPATH, 512, 0, stream>>>(x, cw, cb, (__hip_bfloat16*)sigbf);
    gemm1_kernel<<<dim3(8, ksplit), 256, 0, stream>>>(sigbf, w0, part, nsub);
    red1_kernel<<<512, 256, 0, stream>>>(part, b0, z1, ksplit);
    tail_kernel<<<64, 256, 0, stream>>>(z1, w1, b1, w2, b2, out);
}

// Round 21
// 63.395 us; speedup vs baseline: 1.3180x; 1.1415x over previous
//
#include <hip/hip_runtime.h>
#include <hip/hip_bf16.h>
#include <math.h>

#define TT 128
#define IN_CH 32
#define NPATH 256
#define SIGCH 7380
#define K1 29520
#define N1 512
#define N2 256

typedef __attribute__((ext_vector_type(8))) short bf16x8;
typedef __attribute__((ext_vector_type(8))) unsigned short u16x8;
typedef __attribute__((ext_vector_type(4))) float f32x4;

static __device__ __forceinline__ unsigned pack2bf(float a, float b) {
    union { __hip_bfloat162 h2; unsigned u; } cv;
    cv.h2.x = __float2bfloat16(a);
    cv.h2.y = __float2bfloat16(b);
    return cv.u;
}

// ---------------- Kernel 1: conv + time-augment + depth-4 signature ----------------
// r16 structure (512 thr, 2-way Chen split). Output bf16, but emitted via the
// LDS merge buffers with a cooperative coalesced dword store (r20 wrote ~34
// scattered 2B stores/thread — that was the regression).
__global__ __launch_bounds__(512, 1) void sig_kernel(const float* __restrict__ x,
        const float* __restrict__ cw, const float* __restrict__ cb,
        __hip_bfloat16* __restrict__ sigbf /*[256][7380] bf16*/) {
    __shared__ float incT[9][132];
    __shared__ __align__(16) float sb1[12];
    __shared__ __align__(16) float sb2[9][12];
    __shared__ __align__(16) float sb3[81][12];
    __shared__ __align__(16) float sb4[729][12];
    const int p = blockIdx.x;
    const int b = p >> 2, oc = p & 3;
    const int tid = threadIdx.x;

    const float4 wv = *(const float4*)(cw + oc * 4);
    const float bias = cb[oc];
    const float* xb = x + (long)b * TT * IN_CH;

    for (int it = tid; it < TT * 8; it += 512) {
        const int t = it >> 3, ch = it & 7;
        const float4 xa = *(const float4*)(xb + t * IN_CH + ch * 4);
        float v = xa.x * wv.x + xa.y * wv.y + xa.z * wv.z + xa.w * wv.w + bias;
        if (t > 0) {
            const float4 xm = *(const float4*)(xb + (t - 1) * IN_CH + ch * 4);
            v -= xm.x * wv.x + xm.y * wv.y + xm.z * wv.z + xm.w * wv.w + bias;
        }
        incT[1 + ch][t] = v;
    }
    if (tid < TT) incT[0][tid] = tid ? (1.f / 127.f) : 0.f;
    __syncthreads();

    const int g = tid >> 8;
    const int gtid = tid & 255;
    const bool act = gtid < 243;
    const int base3 = 3 * gtid;
    const int i1 = base3 / 81;
    const int i2 = (base3 / 9) % 9;
    const int i30 = base3 % 9;

    float S4[3][9] = {};
    float s3[3] = {0.f, 0.f, 0.f};
    float s2 = 0.f, s1 = 0.f;

#define LD(R, T4) (*(const float4*)&incT[(R)][(T4)])
#define STEP4(CMP) do { \
    const float E1 = e1v.CMP, E2 = e2v.CMP; \
    const float F0 = f0v.CMP, F1 = f1v.CMP, F2 = f2v.CMP; \
    const float t12 = E1 * E2; \
    const float s1d2 = s1 * E2; \
    const float Ak = t12 * (1.f / 24.f) + s1d2 * (1.f / 6.f) + s2 * 0.5f; \
    const float Bk = t12 * (1.f / 6.f) + s1d2 * 0.5f + s2; \
    const float K0 = F0 * Ak + s3[0]; \
    const float K1v = F1 * Ak + s3[1]; \
    const float K2v = F2 * Ak + s3[2]; \
    _Pragma("unroll") \
    for (int c = 0; c < 9; ++c) { \
        const float Ac = A4[c].CMP; \
        S4[0][c] += K0 * Ac; S4[1][c] += K1v * Ac; S4[2][c] += K2v * Ac; \
    } \
    s3[0] += Bk * F0; s3[1] += Bk * F1; s3[2] += Bk * F2; \
    s2 += E2 * (0.5f * E1 + s1); \
    s1 += E1; \
} while (0)

    if (act) {
        const int t0g = g * 64;
        for (int gg = 0; gg < 16; ++gg) {
            const int t4 = t0g + gg * 4;
            float4 A4[9];
#pragma unroll
            for (int c = 0; c < 9; ++c) A4[c] = LD(c, t4);
            const float4 e1v = LD(i1, t4), e2v = LD(i2, t4);
            const float4 f0v = LD(i30, t4), f1v = LD(i30 + 1, t4), f2v = LD(i30 + 2, t4);
            STEP4(x); STEP4(y); STEP4(z); STEP4(w);
        }
    }
#undef STEP4
#undef LD

    // group 1 publishes its partial into sb*
    if (act && g == 1) {
        if (i2 == 0 && i30 == 0) sb1[i1] = s1;
        if (i30 == 0) sb2[i1][i2] = s2;
#pragma unroll
        for (int q = 0; q < 3; ++q) sb3[i1 * 9 + i2][i30 + q] = s3[q];
#pragma unroll
        for (int q = 0; q < 3; ++q)
#pragma unroll
            for (int c = 0; c < 9; ++c) sb4[base3 + q][c] = S4[q][c];
    }
    __syncthreads();

    // group 0 merges A (x) B into registers
    if (act && g == 0) {
        float S1B[9];
#pragma unroll
        for (int c = 0; c < 9; ++c) S1B[c] = sb1[c];
#pragma unroll
        for (int q = 0; q < 3; ++q) {
            const float* r2 = sb2[i30 + q];
            const float* r3 = sb3[i2 * 9 + i30 + q];
            const float* r4 = sb4[base3 + q];
#pragma unroll
            for (int c = 0; c < 9; ++c)
                S4[q][c] += s3[q] * S1B[c] + s2 * r2[c] + s1 * r3[c] + r4[c];
        }
#pragma unroll
        for (int q = 0; q < 3; ++q)
            s3[q] += s2 * S1B[i30 + q] + s1 * sb2[i2][i30 + q] + sb3[i1 * 9 + i2][i30 + q];
        s2 += s1 * S1B[i2] + sb2[i1][i2];
        s1 += S1B[i1];
    }
    __syncthreads();   // all merge reads of sb* complete

    // group 0 publishes FINAL signature into sb*
    if (act && g == 0) {
        if (i2 == 0 && i30 == 0) sb1[i1] = s1;
        if (i30 == 0) sb2[i1][i2] = s2;
#pragma unroll
        for (int q = 0; q < 3; ++q) sb3[i1 * 9 + i2][i30 + q] = s3[q];
#pragma unroll
        for (int q = 0; q < 3; ++q)
#pragma unroll
            for (int c = 0; c < 9; ++c) sb4[base3 + q][c] = S4[q][c];
    }
    __syncthreads();

    // cooperative coalesced bf16 store: 3690 dwords, all 512 threads
    {
        unsigned* sp = (unsigned*)(sigbf + (long)p * SIGCH);  // 4B-aligned
        for (int j = tid; j < SIGCH / 2; j += 512) {
            const int idx = 2 * j;
            float v0, v1;
#define RD(IDX, V) do { \
            const int ix_ = (IDX); \
            if (ix_ < 9) V = sb1[ix_]; \
            else if (ix_ < 90) { const int jj = ix_ - 9;  V = sb2[jj / 9][jj % 9]; } \
            else if (ix_ < 819) { const int jj = ix_ - 90; V = sb3[jj / 9][jj % 9]; } \
            else { const int jj = ix_ - 819; V = sb4[jj / 9][jj % 9]; } } while (0)
            RD(idx, v0);
            RD(idx + 1, v1);
#undef RD
            sp[j] = pack2bf(v0, v1);
        }
    }
}

// ---------------- Kernel 2: GEMM1 partials via bf16 MFMA (r20, unchanged) ----------------
__global__ __launch_bounds__(256) void gemm1_kernel(const unsigned short* __restrict__ zsig,
        const float* __restrict__ w0, float* __restrict__ part, int nsub) {
    __shared__ unsigned short za[64][136];
    __shared__ unsigned short wb[64][136];
    const int nq = blockIdx.x;            // 0..7
    const int n0 = nq * 64;
    const int tid = threadIdx.x;
    const int lane = tid & 63;
    const int wvid = __builtin_amdgcn_readfirstlane(tid >> 6);  // 0..3
    const int r0 = wvid * 16;
    const int rA = lane & 15, gr = lane >> 4;

    {   // zero k-pad [120,128) once
        const int row = tid >> 2, off = 120 + 2 * (tid & 3);
        *(unsigned*)&za[row][off] = 0u;
        *(unsigned*)&wb[row][off] = 0u;
    }

    f32x4 acc[4];
#pragma unroll
    for (int t = 0; t < 4; ++t) acc[t] = (f32x4){0.f, 0.f, 0.f, 0.f};

    for (int s = 0; s < nsub; ++s) {
        const int kb = (blockIdx.y * nsub + s) * 120;
        if (s) __syncthreads();
        // stage z: 64 rows x 15 ushort8 segments = 960 (16B/lane)
#pragma unroll
        for (int j = 0; j < 4; ++j) {
            const int i = tid + j * 256;
            if (i < 960) {
                const int row = i / 15, seg = i % 15;
                *(u16x8*)&za[row][seg * 8] =
                    *(const u16x8*)(zsig + (long)row * K1 + kb + seg * 8);
            }
        }
        // stage w: 60 kp x 16 col-quads = 960; float4-pair loads + pack
#pragma unroll
        for (int j = 0; j < 4; ++j) {
            const int i = tid + j * 256;
            if (i < 960) {
                const int kp = i >> 4, cq = (i & 15) * 4;
                const float4 ra = *(const float4*)(w0 + (long)(kb + 2 * kp) * N1 + n0 + cq);
                const float4 rb = *(const float4*)(w0 + (long)(kb + 2 * kp + 1) * N1 + n0 + cq);
                *(unsigned*)&wb[cq + 0][2 * kp] = pack2bf(ra.x, rb.x);
                *(unsigned*)&wb[cq + 1][2 * kp] = pack2bf(ra.y, rb.y);
                *(unsigned*)&wb[cq + 2][2 * kp] = pack2bf(ra.z, rb.z);
                *(unsigned*)&wb[cq + 3][2 * kp] = pack2bf(ra.w, rb.w);
            }
        }
        __syncthreads();
#pragma unroll
        for (int ks = 0; ks < 4; ++ks) {
            const bf16x8 af = *(const bf16x8*)&za[r0 + rA][ks * 32 + gr * 8];
#pragma unroll
            for (int t = 0; t < 4; ++t) {
                const bf16x8 bf = *(const bf16x8*)&wb[16 * t + rA][ks * 32 + gr * 8];
                acc[t] = __builtin_amdgcn_mfma_f32_16x16x32_bf16(af, bf, acc[t], 0, 0, 0);
            }
        }
    }

    // D: row = r0 + 4*gr + j, col = n0 + 16*t + rA
    float* pp = part + ((long)blockIdx.y * 64 + r0 + 4 * gr) * N1 + n0 + rA;
#pragma unroll
    for (int t = 0; t < 4; ++t)
#pragma unroll
        for (int j = 0; j < 4; ++j)
            pp[(long)j * N1 + 16 * t] = acc[t][j];
}

// ---------------- Kernel 3: reduce partials + bias + sigmoid ----------------
__global__ __launch_bounds__(256) void red1_kernel(const float* __restrict__ part,
        const float* __restrict__ b0v, float* __restrict__ z1, int ksplit) {
    __shared__ float4 red[256];
    const int tid = threadIdx.x;
    const int cellL = tid & 15, slice = tid >> 4;
    const int cell = blockIdx.x * 16 + cellL;
    const int per = (ksplit + 15) >> 4;
    const int ks = slice * per, ke = min(ksplit, ks + per);
    float4 a = make_float4(0.f, 0.f, 0.f, 0.f);
    for (int kc = ks; kc < ke; kc++) {
        const float4 pv = *(const float4*)(part + ((long)kc * 8192 + cell) * 4);
        a.x += pv.x; a.y += pv.y; a.z += pv.z; a.w += pv.w;
    }
    red[tid] = a;
    __syncthreads();
    if (tid < 128) { float4 o = red[tid + 128]; red[tid].x += o.x; red[tid].y += o.y; red[tid].z += o.z; red[tid].w += o.w; }
    __syncthreads();
    if (tid < 64) { float4 o = red[tid + 64]; red[tid].x += o.x; red[tid].y += o.y; red[tid].z += o.z; red[tid].w += o.w; }
    __syncthreads();
    if (tid < 32) { float4 o = red[tid + 32]; red[tid].x += o.x; red[tid].y += o.y; red[tid].z += o.z; red[tid].w += o.w; }
    __syncthreads();
    if (tid < 16) {
        float4 sum = red[tid];
        float4 o = red[tid + 16];
        sum.x += o.x; sum.y += o.y; sum.z += o.z; sum.w += o.w;
        const float4 bv = *(const float4*)(b0v + (cell & 127) * 4);
        float4 r;
        r.x = 1.f / (1.f + expf(-(sum.x + bv.x)));
        r.y = 1.f / (1.f + expf(-(sum.y + bv.y)));
        r.z = 1.f / (1.f + expf(-(sum.z + bv.z)));
        r.w = 1.f / (1.f + expf(-(sum.w + bv.w)));
        *(float4*)(z1 + cell * 4) = r;
    }
}

// ---------------- Kernel 4: GEMM2 + bias + sigmoid (256 blocks, r18 proven) ----------------
__global__ __launch_bounds__(256) void gemm2_kernel(const float* __restrict__ z1,
        const float* __restrict__ w1, const float* __restrict__ b1v,
        float* __restrict__ z2) {
    __shared__ float red[256];
    const int m = blockIdx.x >> 2, nq = blockIdx.x & 3;
    const int tid = threadIdx.x;
    const int c = tid & 63, s = tid >> 6;
    const int n = nq * 64 + c;
    const float* zr = z1 + m * N1 + s * 128;
    const float* wr = w1 + (long)(s * 128) * N2 + n;
    float acc = 0.f;
#pragma unroll 16
    for (int k = 0; k < 128; k++) acc += zr[k] * wr[(long)k * N2];
    red[tid] = acc;
    __syncthreads();
    if (tid < 128) red[tid] += red[tid + 128];
    __syncthreads();
    if (tid < 64) {
        float sum = red[tid] + red[tid + 64] + b1v[n];
        z2[m * N2 + n] = 1.f / (1.f + expf(-sum));
    }
}

// ---------------- Kernel 5: GEMM3 + log_softmax ----------------
__global__ __launch_bounds__(64) void head_kernel(const float* __restrict__ z2,
        const float* __restrict__ w2, const float* __restrict__ b2v,
        float* __restrict__ out) {
    const int m = blockIdx.x;
    const int tid = threadIdx.x;
    __shared__ float logits[10];
    if (tid < 10) {
        float s = b2v[tid];
        const float* zr = z2 + m * N2;
#pragma unroll 8
        for (int k = 0; k < N2; k++) s += zr[k] * w2[k * 10 + tid];
        logits[tid] = s;
    }
    __syncthreads();
    if (tid == 0) {
        float mx = logits[0];
        for (int j = 1; j < 10; j++) mx = fmaxf(mx, logits[j]);
        float sum = 0.f;
        for (int j = 0; j < 10; j++) sum += expf(logits[j] - mx);
        const float lse = mx + logf(sum);
        for (int j = 0; j < 10; j++) out[m * 10 + j] = logits[j] - lse;
    }
}

extern "C" void kernel_launch(void* const* d_in, const int* in_sizes, int n_in,
                              void* d_out, int out_size, void* d_ws, size_t ws_size,
                              hipStream_t stream) {
    const float* x  = (const float*)d_in[0];
    const float* cw = (const float*)d_in[1];
    const float* cb = (const float*)d_in[2];
    const float* w0 = (const float*)d_in[3];
    const float* b0 = (const float*)d_in[4];
    const float* w1 = (const float*)d_in[5];
    const float* b1 = (const float*)d_in[6];
    const float* w2 = (const float*)d_in[7];
    const float* b2 = (const float*)d_in[8];

    // sig stored as bf16 (256*7380 ushorts = 944,640 floats)
    const size_t sig_floats = (size_t)NPATH * SIGCH / 2;
    const size_t fixed = sig_floats + 64 * N1 + 64 * N2;
    int ksplit = 41, nsub = 6;
    if (ws_size >= (fixed + (size_t)123 * 64 * N1) * 4)      { ksplit = 123; nsub = 2; }
    else if (ws_size >= (fixed + (size_t)82 * 64 * N1) * 4)  { ksplit = 82;  nsub = 3; }

    float* ws   = (float*)d_ws;
    unsigned short* sigbf = (unsigned short*)ws;      // 256 x 7380 bf16
    float* part = ws + sig_floats;                    // ksplit*64*512
    float* z1   = part + (long)ksplit * 64 * N1;      // 64*512
    float* z2   = z1 + 64 * N1;                       // 64*256
    float* out  = (float*)d_out;

    sig_kernel<<<NPATH, 512, 0, stream>>>(x, cw, cb, (__hip_bfloat16*)sigbf);
    gemm1_kernel<<<dim3(8, ksplit), 256, 0, stream>>>(sigbf, w0, part, nsub);
    red1_kernel<<<512, 256, 0, stream>>>(part, b0, z1, ksplit);
    gemm2_kernel<<<256, 256, 0, stream>>>(z1, w1, b1, z2);
    head_kernel<<<64, 64, 0, stream>>>(z2, w2, b2, out);
}